// Round 8
// baseline (63.636 us; speedup 1.0000x reference)
//
#include <hip/hip_runtime.h>
#include <hip/hip_bf16.h>
#include <stdint.h>

// Problem constants
#define BB 64      // batch
#define LL 256     // x seq len
#define TT 64      // y seq len
#define DD 512     // input dim
#define EE 200     // embed dim
#define EP 208     // embed dim padded to 13*16 (32x32x16 MFMA K-granularity)
#define NKK 13     // K-steps in pair kernel (EP/16)
#define NROWS_X 16384   // 64*256
// Fragment-chunk layout: 1 chunk = 32 rows x 16 e = 64 lanes x 16 B = 1024 B.
// lane l holds row (l&31), e_local (l>>5)*8 .. +8, at shorts chunk*512 + l*8.
// Unified pT: chunk index = (global_row >> 5)*13 + n (x rows first, then y).
// ypT starts at chunk 6656 ( = (16384>>5)*13 ).
#define YCH_PER_J (2 * NKK * 64)   // 16B-units per j slice = 1664
#define BSTRIDE 264                // proj bounce row stride in shorts

typedef __attribute__((ext_vector_type(8))) short short8;
typedef __attribute__((ext_vector_type(4))) float floatx4;
typedef __attribute__((ext_vector_type(16))) float floatx16;

__device__ __forceinline__ short f2bf(float f) {
  uint32_t u = __builtin_bit_cast(uint32_t, f);
  u = (u + 0x7fffu + ((u >> 16) & 1u)) >> 16;  // RNE
  return (short)u;
}

// Pack two f32 (truncating to bf16) into one u32 with a single v_perm.
__device__ __forceinline__ uint32_t pack2(float lo, float hi) {
  return __builtin_amdgcn_perm(__builtin_bit_cast(uint32_t, hi),
                               __builtin_bit_cast(uint32_t, lo), 0x07060302u);
}

typedef const __attribute__((address_space(1))) uint32_t gu32_t;
typedef __attribute__((address_space(3))) uint32_t lu32_t;
__device__ __forceinline__ void glds16(const void* g, void* l) {
  __builtin_amdgcn_global_load_lds((gu32_t*)g, (lu32_t*)l, 16, 0, 0);
}

// ---------------- Kernel 0: W (200x512 f32) -> Wb (208x512 bf16, zero-padded), RNE
__global__ void wcvt_kernel(const float* __restrict__ W, short* __restrict__ Wb) {
  const int t = blockIdx.x * 256 + threadIdx.x;   // 0 .. 13311
  const int base = t * 8;
  const int e = base >> 9;
  short8 o;
  if (e < EE) {
    const floatx4 f0 = *(const floatx4*)(W + base);
    const floatx4 f1 = *(const floatx4*)(W + base + 4);
    o[0] = f2bf(f0.x); o[1] = f2bf(f0.y); o[2] = f2bf(f0.z); o[3] = f2bf(f0.w);
    o[4] = f2bf(f1.x); o[5] = f2bf(f1.y); o[6] = f2bf(f1.z); o[7] = f2bf(f1.w);
  } else {
    o = (short8)0;
  }
  *(short8*)(Wb + base) = o;
}

// ---------------- Kernel 1: projection GEMM -> fragment-layout pT (R6 version)
// M=20480 rows (x then y), N=208, K=512. 256 thr = 4 waves, wave = 16 rows x 208 E.
// BM=64, BK=32, double-buffered global_load_lds. Epilogue: LDS bounce ->
// 16B coalesced fragment stores. 43KB LDS -> 3 blocks/CU.
__global__ __launch_bounds__(256, 3) void proj_kernel(const float* __restrict__ x,
                                                      const float* __restrict__ y,
                                                      const short* __restrict__ Wb,
                                                      const float* __restrict__ bias,
                                                      short* __restrict__ pT) {
  __shared__ __align__(16) char smem[43008];
  float* ldsA = (float*)smem;              // [2][64*32]  16,384 B
  short* ldsB = (short*)(smem + 16384);    // [2][208*32] 26,624 B
  short* bounce = (short*)smem;            // [64][BSTRIDE] 33,792 B (after loop)

  const int tid  = threadIdx.x;
  const int lane = tid & 63;
  const int wid  = tid >> 6;
  const int r16   = lane & 15;
  const int khalf = lane >> 4;        // 0..3

  const int row0 = blockIdx.x * 64;
  const float* srcbase = (row0 < NROWS_X) ? (x + (size_t)row0 * DD)
                                          : (y + (size_t)(row0 - NROWS_X) * DD);

  floatx4 acc[NKK];
#pragma unroll
  for (int n = 0; n < NKK; n++) acc[n] = (floatx4){0.f, 0.f, 0.f, 0.f};

  // Stage K-step ks. ldsA[r][c16] <- x[r][ks*32 + (c^(r&7))*4 ..+4)
  //                  ldsB[e][c16] <- Wb[e][ks*32 + (c^(e&3))*8 ..+8)
  auto stage = [&](int buf, int ks) {
#pragma unroll
    for (int it = 0; it < 2; it++) {
      const int p = it * 256 + tid;
      const int r = p >> 3, c = p & 7;
      glds16(srcbase + (size_t)r * DD + ks * 32 + ((c ^ (r & 7)) << 2),
             &ldsA[buf * 2048 + p * 4]);
    }
#pragma unroll
    for (int it = 0; it < 4; it++) {
      const int p = it * 256 + tid;
      if (p < 832) {
        const int r = p >> 2, c = p & 3;
        glds16(Wb + (size_t)r * DD + ks * 32 + ((c ^ (r & 3)) << 3),
               &ldsB[buf * 6656 + p * 8]);
      }
    }
  };

  stage(0, 0);

  for (int s = 0; s < 16; s++) {
    __syncthreads();
    if (s + 1 < 16) stage((s + 1) & 1, s + 1);

    const int buf = s & 1;
    const int r = wid * 16 + r16;
    const int c0 = (2 * khalf) ^ (r & 7);
    const int c1 = (2 * khalf + 1) ^ (r & 7);
    const floatx4 f0 = *(const floatx4*)&ldsA[buf * 2048 + r * 32 + c0 * 4];
    const floatx4 f1 = *(const floatx4*)&ldsA[buf * 2048 + r * 32 + c1 * 4];
    union { short8 s8; uint32_t u[4]; } af;
    af.u[0] = pack2(f0.x, f0.y);
    af.u[1] = pack2(f0.z, f0.w);
    af.u[2] = pack2(f1.x, f1.y);
    af.u[3] = pack2(f1.z, f1.w);
#pragma unroll
    for (int n = 0; n < NKK; n++) {
      const int erow = n * 16 + r16;
      const short8 bfrag = *(const short8*)&ldsB[buf * 6656 + erow * 32 + ((khalf ^ (erow & 3)) << 3)];
      acc[n] = __builtin_amdgcn_mfma_f32_16x16x32_bf16(af.s8, bfrag, acc[n], 0, 0, 0);
    }
  }

  __syncthreads();   // all LDS reads done; safe to reuse smem as bounce

  // Epilogue 1: bias + f2bf -> bounce[lr][e]
#pragma unroll
  for (int n = 0; n < NKK; n++) {
    const int e = n * 16 + r16;
    const float bv = (e < EE) ? bias[e] : 0.0f;
#pragma unroll
    for (int rr = 0; rr < 4; rr++) {
      const int lr = wid * 16 + khalf * 4 + rr;
      bounce[lr * BSTRIDE + e] = f2bf(acc[n][rr] + bv);
    }
  }
  __syncthreads();

  // Epilogue 2: read fragment pieces (16B) and store coalesced into chunk layout.
  const int rowblk0 = row0 >> 5;
  for (int c = tid; c < 1664; c += 256) {
    const int q  = c >> 6;
    const int mt = (q >= 13) ? 1 : 0;
    const int n  = q - mt * 13;
    const int l  = c & 63;
    const int lr = mt * 32 + (l & 31);
    const short8 piece = *(const short8*)&bounce[lr * BSTRIDE + n * 16 + (l >> 5) * 8];
    *(short8*)&pT[((size_t)((rowblk0 + mt) * 13 + n)) * 512 + l * 8] = piece;
  }
}

// ---------------- Kernel 2: pair kernel, Bi=4 x Bj=4, grid 256 = 1 block/CU,
// 1024 thr = 16 waves (4/SIMD). Wave = (lt = wid&7: one 32-row L-tile) x
// (jh = wid>>3: j-half). Per kk: 1 A-load + 4 LDS reads + 4 MFMA -> per-CU
// A-traffic 16 KB/kk (L2 budget ok), acc = 64 VGPR -> fits 128-reg cap.
// XCD-grouped: 16 blocks sharing an i-group land on one XCD (A set 416 KB << L2).
__global__ __launch_bounds__(1024, 4) void pair_kernel(const short* __restrict__ xpT,
                                                       const short* __restrict__ ypT,
                                                       float* __restrict__ S) {
  __shared__ __align__(16) char ldsbuf[106496 + 32768];
  short* ylds = (short*)ldsbuf;                  // 104 chunks: (jl*2+nt)*13+kk
  float* red  = (float*)(ldsbuf + 106496);       // [lt][ii][jl][64 t]

  const int tid  = threadIdx.x;
  const int lane = tid & 63;
  const int wid  = tid >> 6;         // 0..15
  const int lt   = wid & 7;          // L-tile (32 rows)
  const int jh   = wid >> 3;         // j-half
  const int bid  = blockIdx.x;
  const int igrp = ((bid & 7) << 1) | ((bid >> 3) & 1);  // 16 blocks/igrp on one XCD
  const int jgrp = bid >> 4;
  const int ibase = igrp * 4;
  const int j0    = jgrp * 4;

  // Stage 4 j-slices: 4*1664 = 6656 16B-units (wave-uniform trip counts).
  {
    const short* src = ypT + (size_t)j0 * YCH_PER_J * 8;
    for (int c = tid; c < 4 * YCH_PER_J; c += 1024) {
      glds16(src + (size_t)c * 8, ldsbuf + c * 16);
    }
  }
  __syncthreads();

  for (int ii = 0; ii < 4; ii++) {
    const int i = ibase + ii;

    floatx16 acc[2][2];              // [jjj][nt]
#pragma unroll
    for (int jjj = 0; jjj < 2; jjj++)
#pragma unroll
      for (int nt = 0; nt < 2; nt++)
#pragma unroll
        for (int r = 0; r < 16; r++) acc[jjj][nt][r] = 0.f;

    const short* abase = xpT + ((size_t)((i * 8 + lt) * NKK) * 512) + lane * 8;

#pragma unroll
    for (int kk = 0; kk < NKK; kk++) {
      const short8 a = *(const short8*)(abase + kk * 512);
#pragma unroll
      for (int jjj = 0; jjj < 2; jjj++) {
#pragma unroll
        for (int nt = 0; nt < 2; nt++) {
          const int jl = jh * 2 + jjj;
          const short8 bf = *(const short8*)(ylds + ((size_t)((jl * 2 + nt) * NKK + kk)) * 512 + lane * 8);
          acc[jjj][nt] = __builtin_amdgcn_mfma_f32_32x32x16_bf16(a, bf, acc[jjj][nt], 0, 0, 0);
        }
      }
    }

    // Max over this wave's 32 L-rows per column t (C layout: col = lane&31).
#pragma unroll
    for (int jjj = 0; jjj < 2; jjj++) {
#pragma unroll
      for (int nt = 0; nt < 2; nt++) {
        float v = acc[jjj][nt][0];
#pragma unroll
        for (int r = 1; r < 16; r++) v = fmaxf(v, acc[jjj][nt][r]);
        v = fmaxf(v, __shfl_xor(v, 32, 64));
        if (lane < 32) {
          const int jl = jh * 2 + jjj;
          red[((lt * 4 + ii) * 4 + jl) * 64 + nt * 32 + lane] = v;
        }
      }
    }
  }
  __syncthreads();

  // Final: 16 (ii,jl) combos x 64 t; wave wid takes combo wid.
  {
    const int ii = wid >> 2;
    const int jl = wid & 3;
    const int t  = lane;
    float v = red[((0 * 4 + ii) * 4 + jl) * 64 + t];
#pragma unroll
    for (int l2 = 1; l2 < 8; l2++)
      v = fmaxf(v, red[((l2 * 4 + ii) * 4 + jl) * 64 + t]);
    v += __shfl_xor(v, 1, 64);
    v += __shfl_xor(v, 2, 64);
    v += __shfl_xor(v, 4, 64);
    v += __shfl_xor(v, 8, 64);
    v += __shfl_xor(v, 16, 64);
    v += __shfl_xor(v, 32, 64);
    if (t == 0) S[(ibase + ii) * BB + j0 + jl] = v * (1.0f / 64.0f);
  }
}

extern "C" void kernel_launch(void* const* d_in, const int* in_sizes, int n_in,
                              void* d_out, int out_size, void* d_ws, size_t ws_size,
                              hipStream_t stream) {
  const float* x = (const float*)d_in[0];   // 64*256*512
  const float* y = (const float*)d_in[1];   // 64*64*512
  const float* W = (const float*)d_in[2];   // 200*512
  const float* b = (const float*)d_in[3];   // 200
  float* S = (float*)d_out;                 // 64*64

  char* ws = (char*)d_ws;
  short* Wb = (short*)ws;                   // 208*512*2 = 212,992 B
  short* pT = (short*)(ws + 262144);        // 8320 chunks * 1024 B = 8,519,680 B
  short* ypT = pT + (size_t)6656 * 512;     // y starts at chunk 6656

  wcvt_kernel<<<52, 256, 0, stream>>>(W, Wb);
  proj_kernel<<<320, 256, 0, stream>>>(x, y, Wb, b, pT);
  pair_kernel<<<256, 1024, 0, stream>>>(pT, ypT, S);
}

// Round 9
// 52.535 us; speedup vs baseline: 1.2113x; 1.2113x over previous
//
#include <hip/hip_runtime.h>
#include <hip/hip_bf16.h>
#include <stdint.h>

// Problem constants
#define BB 64      // batch
#define LL 256     // x seq len
#define TT 64      // y seq len
#define DD 512     // input dim
#define EE 200     // embed dim
#define EP 208     // embed dim padded to 13*16 (32x32x16 MFMA K-granularity)
#define NKK 13     // K-steps in pair kernel (EP/16)
#define NROWS_X 16384   // 64*256
// Fragment-chunk layout: 1 chunk = 32 rows x 16 e = 64 lanes x 16 B = 1024 B.
// lane l holds row (l&31), e_local (l>>5)*8 .. +8, at shorts chunk*512 + l*8.
// Unified pT: chunk index = (global_row >> 5)*13 + n (x rows first, then y).
// Per i: 104 chunks (8 lt x 13 kk). Per j: 26 chunks (2 nt x 13 kk).
#define BSTRIDE 264                // proj bounce row stride in shorts

typedef __attribute__((ext_vector_type(8))) short short8;
typedef __attribute__((ext_vector_type(4))) float floatx4;
typedef __attribute__((ext_vector_type(16))) float floatx16;

__device__ __forceinline__ short f2bf(float f) {
  uint32_t u = __builtin_bit_cast(uint32_t, f);
  u = (u + 0x7fffu + ((u >> 16) & 1u)) >> 16;  // RNE
  return (short)u;
}

// Pack two f32 (truncating to bf16) into one u32 with a single v_perm.
__device__ __forceinline__ uint32_t pack2(float lo, float hi) {
  return __builtin_amdgcn_perm(__builtin_bit_cast(uint32_t, hi),
                               __builtin_bit_cast(uint32_t, lo), 0x07060302u);
}

typedef const __attribute__((address_space(1))) uint32_t gu32_t;
typedef __attribute__((address_space(3))) uint32_t lu32_t;
__device__ __forceinline__ void glds16(const void* g, void* l) {
  __builtin_amdgcn_global_load_lds((gu32_t*)g, (lu32_t*)l, 16, 0, 0);
}

// ---------------- Kernel 0: W (200x512 f32) -> Wb (208x512 bf16, zero-padded), RNE
__global__ void wcvt_kernel(const float* __restrict__ W, short* __restrict__ Wb) {
  const int t = blockIdx.x * 256 + threadIdx.x;   // 0 .. 13311
  const int base = t * 8;
  const int e = base >> 9;
  short8 o;
  if (e < EE) {
    const floatx4 f0 = *(const floatx4*)(W + base);
    const floatx4 f1 = *(const floatx4*)(W + base + 4);
    o[0] = f2bf(f0.x); o[1] = f2bf(f0.y); o[2] = f2bf(f0.z); o[3] = f2bf(f0.w);
    o[4] = f2bf(f1.x); o[5] = f2bf(f1.y); o[6] = f2bf(f1.z); o[7] = f2bf(f1.w);
  } else {
    o = (short8)0;
  }
  *(short8*)(Wb + base) = o;
}

// ---------------- Kernel 1: projection GEMM -> fragment-layout pT (R6 version)
__global__ __launch_bounds__(256, 3) void proj_kernel(const float* __restrict__ x,
                                                      const float* __restrict__ y,
                                                      const short* __restrict__ Wb,
                                                      const float* __restrict__ bias,
                                                      short* __restrict__ pT) {
  __shared__ __align__(16) char smem[43008];
  float* ldsA = (float*)smem;              // [2][64*32]  16,384 B
  short* ldsB = (short*)(smem + 16384);    // [2][208*32] 26,624 B
  short* bounce = (short*)smem;            // [64][BSTRIDE] 33,792 B (after loop)

  const int tid  = threadIdx.x;
  const int lane = tid & 63;
  const int wid  = tid >> 6;
  const int r16   = lane & 15;
  const int khalf = lane >> 4;        // 0..3

  const int row0 = blockIdx.x * 64;
  const float* srcbase = (row0 < NROWS_X) ? (x + (size_t)row0 * DD)
                                          : (y + (size_t)(row0 - NROWS_X) * DD);

  floatx4 acc[NKK];
#pragma unroll
  for (int n = 0; n < NKK; n++) acc[n] = (floatx4){0.f, 0.f, 0.f, 0.f};

  auto stage = [&](int buf, int ks) {
#pragma unroll
    for (int it = 0; it < 2; it++) {
      const int p = it * 256 + tid;
      const int r = p >> 3, c = p & 7;
      glds16(srcbase + (size_t)r * DD + ks * 32 + ((c ^ (r & 7)) << 2),
             &ldsA[buf * 2048 + p * 4]);
    }
#pragma unroll
    for (int it = 0; it < 4; it++) {
      const int p = it * 256 + tid;
      if (p < 832) {
        const int r = p >> 2, c = p & 3;
        glds16(Wb + (size_t)r * DD + ks * 32 + ((c ^ (r & 3)) << 3),
               &ldsB[buf * 6656 + p * 8]);
      }
    }
  };

  stage(0, 0);

  for (int s = 0; s < 16; s++) {
    __syncthreads();
    if (s + 1 < 16) stage((s + 1) & 1, s + 1);

    const int buf = s & 1;
    const int r = wid * 16 + r16;
    const int c0 = (2 * khalf) ^ (r & 7);
    const int c1 = (2 * khalf + 1) ^ (r & 7);
    const floatx4 f0 = *(const floatx4*)&ldsA[buf * 2048 + r * 32 + c0 * 4];
    const floatx4 f1 = *(const floatx4*)&ldsA[buf * 2048 + r * 32 + c1 * 4];
    union { short8 s8; uint32_t u[4]; } af;
    af.u[0] = pack2(f0.x, f0.y);
    af.u[1] = pack2(f0.z, f0.w);
    af.u[2] = pack2(f1.x, f1.y);
    af.u[3] = pack2(f1.z, f1.w);
#pragma unroll
    for (int n = 0; n < NKK; n++) {
      const int erow = n * 16 + r16;
      const short8 bfrag = *(const short8*)&ldsB[buf * 6656 + erow * 32 + ((khalf ^ (erow & 3)) << 3)];
      acc[n] = __builtin_amdgcn_mfma_f32_16x16x32_bf16(af.s8, bfrag, acc[n], 0, 0, 0);
    }
  }

  __syncthreads();   // all LDS reads done; safe to reuse smem as bounce

#pragma unroll
  for (int n = 0; n < NKK; n++) {
    const int e = n * 16 + r16;
    const float bv = (e < EE) ? bias[e] : 0.0f;
#pragma unroll
    for (int rr = 0; rr < 4; rr++) {
      const int lr = wid * 16 + khalf * 4 + rr;
      bounce[lr * BSTRIDE + e] = f2bf(acc[n][rr] + bv);
    }
  }
  __syncthreads();

  const int rowblk0 = row0 >> 5;
  for (int c = tid; c < 1664; c += 256) {
    const int q  = c >> 6;
    const int mt = (q >= 13) ? 1 : 0;
    const int n  = q - mt * 13;
    const int l  = c & 63;
    const int lr = mt * 32 + (l & 31);
    const short8 piece = *(const short8*)&bounce[lr * BSTRIDE + n * 16 + (l >> 5) * 8];
    *(short8*)&pT[((size_t)((rowblk0 + mt) * 13 + n)) * 512 + l * 8] = piece;
  }
}

// ---------------- Kernel 2: pair kernel — i-resident-in-LDS structure.
// Block = (i, jq): grid 256 = 64 i x 4 jq. 1024 thr = 16 waves = (lt 0..7, nt 0..1).
// A (full i, 104 chunks = 104 KB) staged in LDS ONCE; B (per-j, 26 chunks)
// double-buffered; red double-buffered. One barrier per j. All per-kk operand
// traffic is LDS -> zero dependence on XCD L2 placement (R8's failure mode).
__global__ __launch_bounds__(1024, 4) void pair_kernel(const short* __restrict__ xpT,
                                                       const short* __restrict__ ypT,
                                                       float* __restrict__ S) {
  __shared__ __align__(16) char lds[163840];          // exactly 160 KiB
  short* Alds = (short*)lds;                          // 104 chunks: lt*13+kk
  float* red  = (float*)(lds + 106496 + 53248);       // [2][8 lt][64 t] = 4 KB
  // Blds buf b at lds + 106496 + b*26624: 26 chunks: nt*13+kk

  const int tid  = threadIdx.x;
  const int lane = tid & 63;
  const int wid  = tid >> 6;       // 0..15
  const int lt   = wid >> 1;       // L-tile (32 rows)
  const int nt   = wid & 1;        // t-half
  const int bid  = blockIdx.x;
  const int i    = bid & 63;       // same-i blocks: bid ≡ i (mod 64) — co-XCD under
  const int jq   = bid >> 6;       // round-robin %8, harmless if mapping differs
  const int jbase = jq * 16;

  // Stage A: 104 chunks = 6656 16B-units (threads < 512 do 7, rest 6)
  {
    const short* src = xpT + (size_t)i * 104 * 512;
    for (int c = tid; c < 6656; c += 1024)
      glds16(src + (size_t)c * 8, lds + c * 16);
  }
  // Stage B for jj=0 into buf 0
  {
    const short* src = ypT + (size_t)jbase * 26 * 512;
    for (int c = tid; c < 1664; c += 1024)
      glds16(src + (size_t)c * 8, lds + 106496 + c * 16);
  }
  __syncthreads();   // drains all glds (vmcnt 0 at barrier)

  const short* amine = Alds + (size_t)(lt * NKK) * 512 + lane * 8;

  for (int jj = 0; jj < 16; jj++) {
    const int buf = jj & 1;

    // Stage B for jj+1 into buf^1 (readers of buf^1 finished before barrier jj-1)
    if (jj + 1 < 16) {
      const short* src = ypT + (size_t)(jbase + jj + 1) * 26 * 512;
      char* dst = lds + 106496 + (buf ^ 1) * 26624;
      for (int c = tid; c < 1664; c += 1024)
        glds16(src + (size_t)c * 8, dst + c * 16);
    }

    // Compute: 13 MFMAs (32x32x16), operands pure-LDS
    floatx16 acc;
#pragma unroll
    for (int r = 0; r < 16; r++) acc[r] = 0.f;
    const short* bmine = (short*)(lds + 106496 + buf * 26624) + (size_t)(nt * NKK) * 512 + lane * 8;
#pragma unroll
    for (int kk = 0; kk < NKK; kk++) {
      const short8 a = *(const short8*)(amine + kk * 512);
      const short8 b = *(const short8*)(bmine + kk * 512);
      acc = __builtin_amdgcn_mfma_f32_32x32x16_bf16(a, b, acc, 0, 0, 0);
    }

    // Max over this wave's 32 L-rows per column t (C layout: col = lane&31)
    float v = acc[0];
#pragma unroll
    for (int r = 1; r < 16; r++) v = fmaxf(v, acc[r]);
    v = fmaxf(v, __shfl_xor(v, 32, 64));
    if (lane < 32)
      red[(buf * 8 + lt) * 64 + nt * 32 + lane] = v;

    __syncthreads();   // red[buf] visible; stage(jj+1) drained

    // Distributed per-j reduce: wave jj reads red[buf] while others start jj+1.
    // Next write to red[buf] is in iteration jj+2, after barrier jj+1, which the
    // reducer reaches only after finishing -> race-free.
    if (wid == jj) {
      float m = red[(buf * 8 + 0) * 64 + lane];
#pragma unroll
      for (int l2 = 1; l2 < 8; l2++)
        m = fmaxf(m, red[(buf * 8 + l2) * 64 + lane]);
      m += __shfl_xor(m, 1, 64);
      m += __shfl_xor(m, 2, 64);
      m += __shfl_xor(m, 4, 64);
      m += __shfl_xor(m, 8, 64);
      m += __shfl_xor(m, 16, 64);
      m += __shfl_xor(m, 32, 64);
      if (lane == 0) S[i * BB + jbase + jj] = m * (1.0f / 64.0f);
    }
  }
}

extern "C" void kernel_launch(void* const* d_in, const int* in_sizes, int n_in,
                              void* d_out, int out_size, void* d_ws, size_t ws_size,
                              hipStream_t stream) {
  const float* x = (const float*)d_in[0];   // 64*256*512
  const float* y = (const float*)d_in[1];   // 64*64*512
  const float* W = (const float*)d_in[2];   // 200*512
  const float* b = (const float*)d_in[3];   // 200
  float* S = (float*)d_out;                 // 64*64

  char* ws = (char*)d_ws;
  short* Wb = (short*)ws;                   // 208*512*2 = 212,992 B
  short* pT = (short*)(ws + 262144);        // 8320 chunks * 1024 B = 8,519,680 B
  short* ypT = pT + (size_t)6656 * 512;     // y starts at chunk 6656

  wcvt_kernel<<<52, 256, 0, stream>>>(W, Wb);
  proj_kernel<<<320, 256, 0, stream>>>(x, y, Wb, b, pT);
  pair_kernel<<<256, 1024, 0, stream>>>(pT, ypT, S);
}

// Round 10
// 47.921 us; speedup vs baseline: 1.3279x; 1.0963x over previous
//
#include <hip/hip_runtime.h>
#include <hip/hip_bf16.h>
#include <stdint.h>

// Problem constants
#define BB 64      // batch
#define LL 256     // x seq len
#define TT 64      // y seq len
#define DD 512     // input dim
#define EE 200     // embed dim
#define EP 208     // embed dim padded to 13*16 (32x32x16 MFMA K-granularity)
#define NKK 13     // K-steps in pair kernel (EP/16)
#define NROWS_X 16384   // 64*256
// Fragment-chunk layout: 1 chunk = 32 rows x 16 e = 64 lanes x 16 B = 1024 B.
// lane l holds row (l&31), e_local (l>>5)*8 .. +8, at shorts chunk*512 + l*8.
// Unified pT: chunk index = (global_row >> 5)*13 + n (x rows first, then y).
// Per i: 104 chunks (8 lt x 13 kk). Per j: 26 chunks (2 nt x 13 kk).
#define BSTRIDE 264                // proj bounce row stride in shorts

typedef __attribute__((ext_vector_type(8))) short short8;
typedef __attribute__((ext_vector_type(4))) float floatx4;
typedef __attribute__((ext_vector_type(16))) float floatx16;

__device__ __forceinline__ short f2bf(float f) {
  uint32_t u = __builtin_bit_cast(uint32_t, f);
  u = (u + 0x7fffu + ((u >> 16) & 1u)) >> 16;  // RNE
  return (short)u;
}

// Pack two f32 (truncating to bf16) into one u32 with a single v_perm.
__device__ __forceinline__ uint32_t pack2(float lo, float hi) {
  return __builtin_amdgcn_perm(__builtin_bit_cast(uint32_t, hi),
                               __builtin_bit_cast(uint32_t, lo), 0x07060302u);
}

typedef const __attribute__((address_space(1))) uint32_t gu32_t;
typedef __attribute__((address_space(3))) uint32_t lu32_t;
__device__ __forceinline__ void glds16(const void* g, void* l) {
  __builtin_amdgcn_global_load_lds((gu32_t*)g, (lu32_t*)l, 16, 0, 0);
}

// ---------------- Kernel 0: W (200x512 f32) -> Wb (208x512 bf16, zero-padded), RNE
__global__ void wcvt_kernel(const float* __restrict__ W, short* __restrict__ Wb) {
  const int t = blockIdx.x * 256 + threadIdx.x;   // 0 .. 13311
  const int base = t * 8;
  const int e = base >> 9;
  short8 o;
  if (e < EE) {
    const floatx4 f0 = *(const floatx4*)(W + base);
    const floatx4 f1 = *(const floatx4*)(W + base + 4);
    o[0] = f2bf(f0.x); o[1] = f2bf(f0.y); o[2] = f2bf(f0.z); o[3] = f2bf(f0.w);
    o[4] = f2bf(f1.x); o[5] = f2bf(f1.y); o[6] = f2bf(f1.z); o[7] = f2bf(f1.w);
  } else {
    o = (short8)0;
  }
  *(short8*)(Wb + base) = o;
}

// ---------------- Kernel 1: projection GEMM -> fragment-layout pT (R6 version)
__global__ __launch_bounds__(256, 3) void proj_kernel(const float* __restrict__ x,
                                                      const float* __restrict__ y,
                                                      const short* __restrict__ Wb,
                                                      const float* __restrict__ bias,
                                                      short* __restrict__ pT) {
  __shared__ __align__(16) char smem[43008];
  float* ldsA = (float*)smem;              // [2][64*32]  16,384 B
  short* ldsB = (short*)(smem + 16384);    // [2][208*32] 26,624 B
  short* bounce = (short*)smem;            // [64][BSTRIDE] 33,792 B (after loop)

  const int tid  = threadIdx.x;
  const int lane = tid & 63;
  const int wid  = tid >> 6;
  const int r16   = lane & 15;
  const int khalf = lane >> 4;        // 0..3

  const int row0 = blockIdx.x * 64;
  const float* srcbase = (row0 < NROWS_X) ? (x + (size_t)row0 * DD)
                                          : (y + (size_t)(row0 - NROWS_X) * DD);

  floatx4 acc[NKK];
#pragma unroll
  for (int n = 0; n < NKK; n++) acc[n] = (floatx4){0.f, 0.f, 0.f, 0.f};

  auto stage = [&](int buf, int ks) {
#pragma unroll
    for (int it = 0; it < 2; it++) {
      const int p = it * 256 + tid;
      const int r = p >> 3, c = p & 7;
      glds16(srcbase + (size_t)r * DD + ks * 32 + ((c ^ (r & 7)) << 2),
             &ldsA[buf * 2048 + p * 4]);
    }
#pragma unroll
    for (int it = 0; it < 4; it++) {
      const int p = it * 256 + tid;
      if (p < 832) {
        const int r = p >> 2, c = p & 3;
        glds16(Wb + (size_t)r * DD + ks * 32 + ((c ^ (r & 3)) << 3),
               &ldsB[buf * 6656 + p * 8]);
      }
    }
  };

  stage(0, 0);

  for (int s = 0; s < 16; s++) {
    __syncthreads();
    if (s + 1 < 16) stage((s + 1) & 1, s + 1);

    const int buf = s & 1;
    const int r = wid * 16 + r16;
    const int c0 = (2 * khalf) ^ (r & 7);
    const int c1 = (2 * khalf + 1) ^ (r & 7);
    const floatx4 f0 = *(const floatx4*)&ldsA[buf * 2048 + r * 32 + c0 * 4];
    const floatx4 f1 = *(const floatx4*)&ldsA[buf * 2048 + r * 32 + c1 * 4];
    union { short8 s8; uint32_t u[4]; } af;
    af.u[0] = pack2(f0.x, f0.y);
    af.u[1] = pack2(f0.z, f0.w);
    af.u[2] = pack2(f1.x, f1.y);
    af.u[3] = pack2(f1.z, f1.w);
#pragma unroll
    for (int n = 0; n < NKK; n++) {
      const int erow = n * 16 + r16;
      const short8 bfrag = *(const short8*)&ldsB[buf * 6656 + erow * 32 + ((khalf ^ (erow & 3)) << 3)];
      acc[n] = __builtin_amdgcn_mfma_f32_16x16x32_bf16(af.s8, bfrag, acc[n], 0, 0, 0);
    }
  }

  __syncthreads();   // all LDS reads done; safe to reuse smem as bounce

#pragma unroll
  for (int n = 0; n < NKK; n++) {
    const int e = n * 16 + r16;
    const float bv = (e < EE) ? bias[e] : 0.0f;
#pragma unroll
    for (int rr = 0; rr < 4; rr++) {
      const int lr = wid * 16 + khalf * 4 + rr;
      bounce[lr * BSTRIDE + e] = f2bf(acc[n][rr] + bv);
    }
  }
  __syncthreads();

  const int rowblk0 = row0 >> 5;
  for (int c = tid; c < 1664; c += 256) {
    const int q  = c >> 6;
    const int mt = (q >= 13) ? 1 : 0;
    const int n  = q - mt * 13;
    const int l  = c & 63;
    const int lr = mt * 32 + (l & 31);
    const short8 piece = *(const short8*)&bounce[lr * BSTRIDE + n * 16 + (l >> 5) * 8];
    *(short8*)&pT[((size_t)((rowblk0 + mt) * 13 + n)) * 512 + l * 8] = piece;
  }
}

// ---------------- Kernel 2: pair kernel — A-in-registers, B-in-LDS.
// Block = (i, jq): grid 256 = 64 i x 4 jq, 512 thr = 8 waves, 1 block/CU.
// Wave = (jj2 = wid>>2: j-slot in 2-j group, wj = wid&3: lt-pair).
// A: wave's 2 L-tiles x 13 kk loaded global->REG once (104 VGPR), zero LDS.
// B: 2-j groups double-buffered in LDS via glds (2 x 53,248 B).
// Per kk: 2 ds_read_b128 -> 4 MFMA (0.5 reads/MFMA; per-CU LDS/j = 106 KB
// = half the MFMA cycle budget -> MFMA-bound).
__global__ __launch_bounds__(512, 2) void pair_kernel(const short* __restrict__ xpT,
                                                      const short* __restrict__ ypT,
                                                      float* __restrict__ S) {
  __shared__ __align__(16) char lds[2 * 53248 + 16384];
  float* red = (float*)(lds + 2 * 53248);   // [j 0..15][wj 0..3][64 t] = 16 KB

  const int tid  = threadIdx.x;
  const int lane = tid & 63;
  const int wid  = tid >> 6;       // 0..7
  const int jj2  = wid >> 2;       // j-slot within 2-j group
  const int wj   = wid & 3;        // lt-pair (covers lt = wj*2, wj*2+1)
  const int bid  = blockIdx.x;
  const int i    = bid & 63;
  const int jq   = bid >> 6;
  const int jbase = jq * 16;

  // A global->reg: 2 L-tiles x 13 kk fragments (coalesced 16B/lane per chunk)
  short8 a0[NKK], a1[NKK];
  {
    const short* ab0 = xpT + ((size_t)((i * 8 + wj * 2 + 0) * NKK)) * 512 + lane * 8;
    const short* ab1 = xpT + ((size_t)((i * 8 + wj * 2 + 1) * NKK)) * 512 + lane * 8;
#pragma unroll
    for (int kk = 0; kk < NKK; kk++) {
      a0[kk] = *(const short8*)(ab0 + kk * 512);
      a1[kk] = *(const short8*)(ab1 + kk * 512);
    }
  }

  // Stage B group g (2 j = 52 chunks = 3328 16B-units) into buf g&1.
  auto stageB = [&](int g) {
    const short* src = ypT + (size_t)(jbase + g * 2) * 26 * 512;
    char* dst = lds + (g & 1) * 53248;
    for (int c = tid; c < 3328; c += 512)
      glds16(src + (size_t)c * 8, dst + c * 16);
  };

  stageB(0);
  __syncthreads();   // drains glds + A-loads wait naturally at first use

  for (int g = 0; g < 8; g++) {
    if (g + 1 < 8) stageB(g + 1);

    const int j = g * 2 + jj2;
    const short* bbase = (const short*)(lds + (g & 1) * 53248) +
                         (size_t)(jj2 * 26 * 512) + lane * 8;

    floatx16 accA0n0, accA0n1, accA1n0, accA1n1;
#pragma unroll
    for (int r = 0; r < 16; r++) {
      accA0n0[r] = 0.f; accA0n1[r] = 0.f; accA1n0[r] = 0.f; accA1n1[r] = 0.f;
    }

#pragma unroll
    for (int kk = 0; kk < NKK; kk++) {
      const short8 b0 = *(const short8*)(bbase + (0 * NKK + kk) * 512);
      const short8 b1 = *(const short8*)(bbase + (1 * NKK + kk) * 512);
      accA0n0 = __builtin_amdgcn_mfma_f32_32x32x16_bf16(a0[kk], b0, accA0n0, 0, 0, 0);
      accA1n0 = __builtin_amdgcn_mfma_f32_32x32x16_bf16(a1[kk], b0, accA1n0, 0, 0, 0);
      accA0n1 = __builtin_amdgcn_mfma_f32_32x32x16_bf16(a0[kk], b1, accA0n1, 0, 0, 0);
      accA1n1 = __builtin_amdgcn_mfma_f32_32x32x16_bf16(a1[kk], b1, accA1n1, 0, 0, 0);
    }

    // Max over this wave's 64 L-rows (2 tiles) per column t; C: col = lane&31.
    float v0 = accA0n0[0], v1 = accA0n1[0];
#pragma unroll
    for (int r = 0; r < 16; r++) {
      v0 = fmaxf(v0, accA0n0[r]); v0 = fmaxf(v0, accA1n0[r]);
      v1 = fmaxf(v1, accA0n1[r]); v1 = fmaxf(v1, accA1n1[r]);
    }
    v0 = fmaxf(v0, __shfl_xor(v0, 32, 64));
    v1 = fmaxf(v1, __shfl_xor(v1, 32, 64));
    if (lane < 32) {
      red[(j * 4 + wj) * 64 + 0 * 32 + lane] = v0;
      red[(j * 4 + wj) * 64 + 1 * 32 + lane] = v1;
    }

    __syncthreads();   // buf (g+1)&1 staged complete; red[j] visible at end
  }

  // Final: wave w reduces j = 2w, 2w+1: max over 4 wj-slices, mean over t.
#pragma unroll
  for (int rep = 0; rep < 2; rep++) {
    const int j = wid * 2 + rep;
    const int t = lane;
    float v = red[(j * 4 + 0) * 64 + t];
    v = fmaxf(v, red[(j * 4 + 1) * 64 + t]);
    v = fmaxf(v, red[(j * 4 + 2) * 64 + t]);
    v = fmaxf(v, red[(j * 4 + 3) * 64 + t]);
    v += __shfl_xor(v, 1, 64);
    v += __shfl_xor(v, 2, 64);
    v += __shfl_xor(v, 4, 64);
    v += __shfl_xor(v, 8, 64);
    v += __shfl_xor(v, 16, 64);
    v += __shfl_xor(v, 32, 64);
    if (t == 0) S[i * BB + jbase + j] = v * (1.0f / 64.0f);
  }
}

extern "C" void kernel_launch(void* const* d_in, const int* in_sizes, int n_in,
                              void* d_out, int out_size, void* d_ws, size_t ws_size,
                              hipStream_t stream) {
  const float* x = (const float*)d_in[0];   // 64*256*512
  const float* y = (const float*)d_in[1];   // 64*64*512
  const float* W = (const float*)d_in[2];   // 200*512
  const float* b = (const float*)d_in[3];   // 200
  float* S = (float*)d_out;                 // 64*64

  char* ws = (char*)d_ws;
  short* Wb = (short*)ws;                   // 208*512*2 = 212,992 B
  short* pT = (short*)(ws + 262144);        // 8320 chunks * 1024 B = 8,519,680 B
  short* ypT = pT + (size_t)6656 * 512;     // y starts at chunk 6656

  wcvt_kernel<<<52, 256, 0, stream>>>(W, Wb);
  proj_kernel<<<320, 256, 0, stream>>>(x, y, Wb, b, pT);
  pair_kernel<<<256, 512, 0, stream>>>(pT, ypT, S);
}